// Round 5
// baseline (92.318 us; speedup 1.0000x reference)
//
#include <hip/hip_runtime.h>

#define I_ITEMS 30490
#define H_HOR 28
#define ROW28 (I_ITEMS * H_HOR)       // floats per store block
#define ROWF4 (ROW28 / 4)             // float4s per store block
#define IPB 32                        // items per block
#define K1_BLOCK 256                  // 32 items * 8 lanes
#define G_ITEM   154
#define G_ISTATE (154 + I_ITEMS)
#define G_ISTORE (154 + 4 * I_ITEMS)

__device__ __forceinline__ float4 f4add(float4 a, float4 b) {
    return make_float4(a.x + b.x, a.y + b.y, a.z + b.z, a.w + b.w);
}
__device__ __forceinline__ float dot4(float4 a) {
    return a.x * a.x + a.y * a.y + a.z * a.z + a.w * a.w;
}
__device__ __forceinline__ float red8(float v) {   // sum over 8-lane group
    v += __shfl_xor(v, 1); v += __shfl_xor(v, 2); v += __shfl_xor(v, 4);
    return v;
}

// ws layout: [0,1960) base sums [store*7+dept][28]; [1960,...) block partials

__global__ __launch_bounds__(K1_BLOCK, 4) void wrmsse_k1(
    const float* __restrict__ inp, const float* __restrict__ tgt,
    const float* __restrict__ scales, const float* __restrict__ weights,
    float* __restrict__ ws_base, float* __restrict__ ws_part)
{
    __shared__ float tb[10 * 2 * 28];   // [store][dsel][h] block-local base sums
    __shared__ float wred[4];
    const int tid  = threadIdx.x;
    const int lane = tid & 63;
    const int wv   = tid >> 6;
    const int grp  = tid >> 3;          // local item 0..31
    const int hq   = tid & 7;           // h-quad; hq==7 carries no data
    const int i0   = blockIdx.x * IPB;
    const int gi   = i0 + grp;
    const bool valid = (gi < I_ITEMS) && (hq < 7);

    const int iLast = min(i0 + IPB - 1, I_ITEMS - 1);
    const int dept0 = (i0 * 7) / I_ITEMS;
    const bool uniform = (dept0 == ((iLast * 7) / I_ITEMS));

    // zero the block table
    for (int t = tid; t < 560; t += K1_BLOCK) tb[t] = 0.0f;

    // ---- 20 unconditional clamped loads, batched before any consumption ----
    const int giC = min(gi, I_ITEMS - 1);
    const int hqC = min(hq, 6);
    const int b0  = giC * 7 + hqC;
    const float4* tp4 = (const float4*)tgt;
    const float4* ip4 = (const float4*)inp;

    float4 A[10], B[10];
    #pragma unroll
    for (int st = 0; st < 10; ++st) A[st] = tp4[st * ROWF4 + b0];
    #pragma unroll
    for (int st = 0; st < 10; ++st) B[st] = ip4[st * ROWF4 + b0];

    __syncthreads();   // tb zeroed before atomics (loads already in flight)

    const float m = valid ? 1.0f : 0.0f;
    const int di   = (giC * 7) / I_ITEMS;
    const int dsel = min(di - dept0, 1);
    float* tbrow = &tb[0];

    float4 ca = make_float4(0.f, 0.f, 0.f, 0.f);
    float4 tx = ca, wi = ca;
    float ss[10];

    #pragma unroll
    for (int st = 0; st < 10; ++st) {
        float4 d = make_float4((A[st].x - B[st].x) * m, (A[st].y - B[st].y) * m,
                               (A[st].z - B[st].z) * m, (A[st].w - B[st].w) * m);
        ss[st] = dot4(d);
        if (st < 4)      ca = f4add(ca, d);
        else if (st < 7) tx = f4add(tx, d);
        else             wi = f4add(wi, d);
        if (valid) {
            float* c0 = &tbrow[(st * 2 + dsel) * 28 + 4 * hq];
            atomicAdd(c0 + 0, d.x); atomicAdd(c0 + 1, d.y);
            atomicAdd(c0 + 2, d.z); atomicAdd(c0 + 3, d.w);
        }
    }

    // ---- full 28-h sums within each 8-lane group ----
    #pragma unroll
    for (int st = 0; st < 10; ++st) ss[st] = red8(ss[st]);
    float sq0 = red8(dot4(ca));
    float sq1 = red8(dot4(tx));
    float sq2 = red8(dot4(wi));
    float sq3 = red8(dot4(f4add(f4add(ca, tx), wi)));

    // ---- per-item group contributions: 14 values over the 8 lanes ----
    float contrib = 0.0f;
    if (gi < I_ITEMS) {
        const int k = hq;
        float v1 = ss[0];
        if (k == 1) v1 = ss[1]; if (k == 2) v1 = ss[2]; if (k == 3) v1 = ss[3];
        if (k == 4) v1 = ss[4]; if (k == 5) v1 = ss[5]; if (k == 6) v1 = ss[6];
        if (k == 7) v1 = ss[7];
        int g1 = G_ISTORE + gi * 10 + k;
        contrib = weights[g1] * sqrtf(v1 / (28.0f * scales[g1]));
        if (k < 6) {
            float v2 = (k == 0) ? ss[8] : (k == 1) ? ss[9] :
                       (k == 2) ? sq0   : (k == 3) ? sq1   :
                       (k == 4) ? sq2   : sq3;
            int g2 = (k < 2) ? (G_ISTORE + gi * 10 + 8 + k)
                   : (k < 5) ? (G_ISTATE + gi * 3 + (k - 2))
                             : (G_ITEM + gi);
            contrib += weights[g2] * sqrtf(v2 / (28.0f * scales[g2]));
        }
    }

    __syncthreads();   // all LDS atomics done

    // ---- flush block table to global (1 row, 2 at dept boundaries) ----
    const int ncell = uniform ? 280 : 560;
    for (int t = tid; t < ncell; t += K1_BLOCK) {
        const int r = t / 280, cell = t % 280;
        const int st = cell / 28, h = cell % 28;
        atomicAdd(&ws_base[(st * 7 + dept0 + r) * 28 + h],
                  tb[(st * 2 + r) * 28 + h]);
    }

    // ---- block contribution reduce ----
    float c = contrib;
    #pragma unroll
    for (int off = 32; off > 0; off >>= 1) c += __shfl_down(c, off, 64);
    if (lane == 0) wred[wv] = c;
    __syncthreads();
    if (tid == 0) ws_part[blockIdx.x] = wred[0] + wred[1] + wred[2] + wred[3];
}

__global__ __launch_bounds__(256) void wrmsse_k2(
    const float* __restrict__ scales, const float* __restrict__ weights,
    const float* __restrict__ ws_base, const float* __restrict__ ws_part,
    const int npart, float* __restrict__ out)
{
    __shared__ float P[28 * 88];   // per-h padded 2D prefix
    __shared__ float red[256];
    const int tid = threadIdx.x;

    float acc = 0.0f;
    for (int p = tid; p < npart; p += 256) acc += ws_part[p];

    if (tid < 28) {
        const int h = tid;
        float v[10][7];
        #pragma unroll
        for (int st = 0; st < 10; ++st)
            #pragma unroll
            for (int dd = 0; dd < 7; ++dd)
                v[st][dd] = ws_base[(st * 7 + dd) * 28 + h];
        #pragma unroll
        for (int st = 0; st < 10; ++st)
            #pragma unroll
            for (int dd = 1; dd < 7; ++dd) v[st][dd] += v[st][dd - 1];
        #pragma unroll
        for (int dd = 0; dd < 7; ++dd)
            #pragma unroll
            for (int st = 1; st < 10; ++st) v[st][dd] += v[st - 1][dd];
        float* Ph = &P[h * 88];
        #pragma unroll
        for (int dd = 0; dd < 8; ++dd) Ph[dd] = 0.0f;
        #pragma unroll
        for (int st = 1; st < 11; ++st) {
            Ph[st * 8] = 0.0f;
            #pragma unroll
            for (int dd = 1; dd < 8; ++dd) Ph[st * 8 + dd] = v[st - 1][dd - 1];
        }
    }
    __syncthreads();

    if (tid < 154) {
        const int g = tid;
        const int st_lo3[3] = {0, 4, 7}, st_hi3[3] = {4, 7, 10};
        const int ct_lo3[3] = {0, 3, 5}, ct_hi3[3] = {3, 5, 7};
        int s_lo, s_hi, d_lo, d_hi;
        if (g == 0)      { s_lo=0; s_hi=10; d_lo=0; d_hi=7; }
        else if (g < 4)  { int s=g-1;  s_lo=st_lo3[s]; s_hi=st_hi3[s]; d_lo=0; d_hi=7; }
        else if (g < 14) { int st=g-4; s_lo=st; s_hi=st+1; d_lo=0; d_hi=7; }
        else if (g < 17) { int c=g-14; s_lo=0; s_hi=10; d_lo=ct_lo3[c]; d_hi=ct_hi3[c]; }
        else if (g < 24) { int dd=g-17; s_lo=0; s_hi=10; d_lo=dd; d_hi=dd+1; }
        else if (g < 33) { int l=g-24, s=l/3, c=l%3;
                           s_lo=st_lo3[s]; s_hi=st_hi3[s]; d_lo=ct_lo3[c]; d_hi=ct_hi3[c]; }
        else if (g < 54) { int l=g-33, s=l/7, dd=l%7;
                           s_lo=st_lo3[s]; s_hi=st_hi3[s]; d_lo=dd; d_hi=dd+1; }
        else if (g < 84) { int l=g-54, st=l/3, c=l%3;
                           s_lo=st; s_hi=st+1; d_lo=ct_lo3[c]; d_hi=ct_hi3[c]; }
        else             { int l=g-84, st=l/7, dd=l%7;
                           s_lo=st; s_hi=st+1; d_lo=dd; d_hi=dd+1; }
        float s = 0.0f;
        #pragma unroll
        for (int h = 0; h < 28; ++h) {
            const float* Ph = &P[h * 88];
            float a = Ph[s_hi * 8 + d_hi] - Ph[s_lo * 8 + d_hi]
                    - Ph[s_hi * 8 + d_lo] + Ph[s_lo * 8 + d_lo];
            s += a * a;
        }
        acc += weights[g] * sqrtf(s / (28.0f * scales[g]));
    }

    red[tid] = acc;
    __syncthreads();
    for (int s = 128; s > 0; s >>= 1) {
        if (tid < s) red[tid] += red[tid + s];
        __syncthreads();
    }
    if (tid == 0) out[0] = red[0];
}

extern "C" void kernel_launch(void* const* d_in, const int* in_sizes, int n_in,
                              void* d_out, int out_size, void* d_ws, size_t ws_size,
                              hipStream_t stream) {
    const float* inp     = (const float*)d_in[0];
    const float* tgt     = (const float*)d_in[1];
    const float* scales  = (const float*)d_in[2];
    const float* weights = (const float*)d_in[3];
    // seg_ids (d_in[4]) and num_segments (d_in[5]) are recomputed analytically.

    float* ws_base = (float*)d_ws;           // 70*28 = 1960 floats
    float* ws_part = ws_base + 1960;         // nblocks floats

    const int nblocks = (I_ITEMS + IPB - 1) / IPB;   // 953

    hipMemsetAsync(ws_base, 0, 1960 * sizeof(float), stream);
    wrmsse_k1<<<nblocks, K1_BLOCK, 0, stream>>>(inp, tgt, scales, weights, ws_base, ws_part);
    wrmsse_k2<<<1, 256, 0, stream>>>(scales, weights, ws_base, ws_part, nblocks, (float*)d_out);
}

// Round 6
// 61.506 us; speedup vs baseline: 1.5010x; 1.5010x over previous
//
#include <hip/hip_runtime.h>

#define I_ITEMS 30490
#define H_HOR 28
#define ROW28 (I_ITEMS * H_HOR)       // floats per store block
#define ROWF4 (ROW28 / 4)             // float4s per store block
#define IPB 32                        // items per block
#define K1_BLOCK 256                  // 32 items * 8 lanes
#define G_ITEM   154
#define G_ISTATE (154 + I_ITEMS)
#define G_ISTORE (154 + 4 * I_ITEMS)

__device__ __forceinline__ float4 f4add(float4 a, float4 b) {
    return make_float4(a.x + b.x, a.y + b.y, a.z + b.z, a.w + b.w);
}
__device__ __forceinline__ float dot4(float4 a) {
    return a.x * a.x + a.y * a.y + a.z * a.z + a.w * a.w;
}
__device__ __forceinline__ float4 shflx4(float4 v, int m) {
    return make_float4(__shfl_xor(v.x, m), __shfl_xor(v.y, m),
                       __shfl_xor(v.z, m), __shfl_xor(v.w, m));
}
__device__ __forceinline__ float red8(float v) {   // sum over 8-lane group
    v += __shfl_xor(v, 1); v += __shfl_xor(v, 2); v += __shfl_xor(v, 4);
    return v;
}

// ws layout: [0,1960) base sums [store*7+dept][28]; [1960,...) block partials

__global__ __launch_bounds__(K1_BLOCK, 4) void wrmsse_k1(
    const float* __restrict__ inp, const float* __restrict__ tgt,
    const float* __restrict__ scales, const float* __restrict__ weights,
    float* __restrict__ ws_base, float* __restrict__ ws_part)
{
    __shared__ float lds_tb[4 * 8 * 40];   // [wave][hq][store*4+c]
    __shared__ float wred[4];
    const int tid  = threadIdx.x;
    const int lane = tid & 63;
    const int wv   = tid >> 6;
    const int grp  = tid >> 3;          // local item 0..31
    const int hq   = tid & 7;           // h-quad; hq==7 carries no data
    const int i0   = blockIdx.x * IPB;
    const int gi   = i0 + grp;
    const bool valid = (gi < I_ITEMS) && (hq < 7);

    const int iLast = min(i0 + IPB - 1, I_ITEMS - 1);
    const int dept0 = (i0 * 7) / I_ITEMS;
    const bool uniform = (dept0 == ((iLast * 7) / I_ITEMS));

    // ---- 20 clamped loads, pinned as one batch by the asm memory fence ----
    const int giC = min(gi, I_ITEMS - 1);
    const int hqC = min(hq, 6);
    const int b0  = giC * 7 + hqC;
    const float4* tp4 = (const float4*)tgt;
    const float4* ip4 = (const float4*)inp;

    float4 A[10], B[10];
    #pragma unroll
    for (int st = 0; st < 10; ++st) A[st] = tp4[st * ROWF4 + b0];
    #pragma unroll
    for (int st = 0; st < 10; ++st) B[st] = ip4[st * ROWF4 + b0];
    asm volatile("" ::: "memory");     // compiler fence: no load sinks below

    const float m = valid ? 1.0f : 0.0f;
    float4 ca = make_float4(0.f, 0.f, 0.f, 0.f);
    float4 tx = ca, wi = ca;
    float ss[10];

    #pragma unroll
    for (int st = 0; st < 10; ++st) {
        float4 d = make_float4((A[st].x - B[st].x) * m, (A[st].y - B[st].y) * m,
                               (A[st].z - B[st].z) * m, (A[st].w - B[st].w) * m);
        ss[st] = dot4(d);
        if (st < 4)      ca = f4add(ca, d);
        else if (st < 7) tx = f4add(tx, d);
        else             wi = f4add(wi, d);
        if (uniform) {
            // butterfly over the 8 item-groups of the wave (masks 8,16,32)
            float4 bf = d;
            bf = f4add(bf, shflx4(bf, 8));
            bf = f4add(bf, shflx4(bf, 16));
            bf = f4add(bf, shflx4(bf, 32));
            if (lane < 7) *(float4*)&lds_tb[(wv * 8 + lane) * 40 + st * 4] = bf;
        } else if (valid) {                         // rare dept-boundary block
            const int di = (giC * 7) / I_ITEMS;
            float* wb = &ws_base[(st * 7 + di) * 28 + 4 * hq];
            atomicAdd(wb + 0, d.x); atomicAdd(wb + 1, d.y);
            atomicAdd(wb + 2, d.z); atomicAdd(wb + 3, d.w);
        }
    }

    // ---- full 28-h sums within each 8-lane group ----
    #pragma unroll
    for (int st = 0; st < 10; ++st) ss[st] = red8(ss[st]);
    float sq0 = red8(dot4(ca));
    float sq1 = red8(dot4(tx));
    float sq2 = red8(dot4(wi));
    float sq3 = red8(dot4(f4add(f4add(ca, tx), wi)));

    // ---- per-item group contributions: 14 values over the 8 lanes ----
    float contrib = 0.0f;
    if (gi < I_ITEMS) {
        const int k = hq;
        float v1 = ss[0];
        if (k == 1) v1 = ss[1]; if (k == 2) v1 = ss[2]; if (k == 3) v1 = ss[3];
        if (k == 4) v1 = ss[4]; if (k == 5) v1 = ss[5]; if (k == 6) v1 = ss[6];
        if (k == 7) v1 = ss[7];
        int g1 = G_ISTORE + gi * 10 + k;
        contrib = weights[g1] * sqrtf(v1 / (28.0f * scales[g1]));
        if (k < 6) {
            float v2 = (k == 0) ? ss[8] : (k == 1) ? ss[9] :
                       (k == 2) ? sq0   : (k == 3) ? sq1   :
                       (k == 4) ? sq2   : sq3;
            int g2 = (k < 2) ? (G_ISTORE + gi * 10 + 8 + k)
                   : (k < 5) ? (G_ISTATE + gi * 3 + (k - 2))
                             : (G_ITEM + gi);
            contrib += weights[g2] * sqrtf(v2 / (28.0f * scales[g2]));
        }
    }

    __syncthreads();   // lds_tb writes visible

    // ---- flush per-block (store,dept0,h) sums: 280 cells over 256 threads ----
    if (uniform) {
        for (int t = tid; t < 280; t += K1_BLOCK) {
            const int st = t / 28, h = t % 28;
            float s = 0.0f;
            #pragma unroll
            for (int w = 0; w < 4; ++w)
                s += lds_tb[(w * 8 + (h >> 2)) * 40 + st * 4 + (h & 3)];
            atomicAdd(&ws_base[(st * 7 + dept0) * 28 + h], s);
        }
    }

    // ---- block contribution reduce ----
    float c = contrib;
    #pragma unroll
    for (int off = 32; off > 0; off >>= 1) c += __shfl_down(c, off, 64);
    if (lane == 0) wred[wv] = c;
    __syncthreads();
    if (tid == 0) ws_part[blockIdx.x] = wred[0] + wred[1] + wred[2] + wred[3];
}

__global__ __launch_bounds__(256) void wrmsse_k2(
    const float* __restrict__ scales, const float* __restrict__ weights,
    const float* __restrict__ ws_base, const float* __restrict__ ws_part,
    const int npart, float* __restrict__ out)
{
    __shared__ float P[28 * 88];   // per-h padded 2D prefix
    __shared__ float red[256];
    const int tid = threadIdx.x;

    float acc = 0.0f;
    for (int p = tid; p < npart; p += 256) acc += ws_part[p];

    if (tid < 28) {
        const int h = tid;
        float v[10][7];
        #pragma unroll
        for (int st = 0; st < 10; ++st)
            #pragma unroll
            for (int dd = 0; dd < 7; ++dd)
                v[st][dd] = ws_base[(st * 7 + dd) * 28 + h];
        #pragma unroll
        for (int st = 0; st < 10; ++st)
            #pragma unroll
            for (int dd = 1; dd < 7; ++dd) v[st][dd] += v[st][dd - 1];
        #pragma unroll
        for (int dd = 0; dd < 7; ++dd)
            #pragma unroll
            for (int st = 1; st < 10; ++st) v[st][dd] += v[st - 1][dd];
        float* Ph = &P[h * 88];
        #pragma unroll
        for (int dd = 0; dd < 8; ++dd) Ph[dd] = 0.0f;
        #pragma unroll
        for (int st = 1; st < 11; ++st) {
            Ph[st * 8] = 0.0f;
            #pragma unroll
            for (int dd = 1; dd < 8; ++dd) Ph[st * 8 + dd] = v[st - 1][dd - 1];
        }
    }
    __syncthreads();

    if (tid < 154) {
        const int g = tid;
        const int st_lo3[3] = {0, 4, 7}, st_hi3[3] = {4, 7, 10};
        const int ct_lo3[3] = {0, 3, 5}, ct_hi3[3] = {3, 5, 7};
        int s_lo, s_hi, d_lo, d_hi;
        if (g == 0)      { s_lo=0; s_hi=10; d_lo=0; d_hi=7; }
        else if (g < 4)  { int s=g-1;  s_lo=st_lo3[s]; s_hi=st_hi3[s]; d_lo=0; d_hi=7; }
        else if (g < 14) { int st=g-4; s_lo=st; s_hi=st+1; d_lo=0; d_hi=7; }
        else if (g < 17) { int c=g-14; s_lo=0; s_hi=10; d_lo=ct_lo3[c]; d_hi=ct_hi3[c]; }
        else if (g < 24) { int dd=g-17; s_lo=0; s_hi=10; d_lo=dd; d_hi=dd+1; }
        else if (g < 33) { int l=g-24, s=l/3, c=l%3;
                           s_lo=st_lo3[s]; s_hi=st_hi3[s]; d_lo=ct_lo3[c]; d_hi=ct_hi3[c]; }
        else if (g < 54) { int l=g-33, s=l/7, dd=l%7;
                           s_lo=st_lo3[s]; s_hi=st_hi3[s]; d_lo=dd; d_hi=dd+1; }
        else if (g < 84) { int l=g-54, st=l/3, c=l%3;
                           s_lo=st; s_hi=st+1; d_lo=ct_lo3[c]; d_hi=ct_hi3[c]; }
        else             { int l=g-84, st=l/7, dd=l%7;
                           s_lo=st; s_hi=st+1; d_lo=dd; d_hi=dd+1; }
        float s = 0.0f;
        #pragma unroll
        for (int h = 0; h < 28; ++h) {
            const float* Ph = &P[h * 88];
            float a = Ph[s_hi * 8 + d_hi] - Ph[s_lo * 8 + d_hi]
                    - Ph[s_hi * 8 + d_lo] + Ph[s_lo * 8 + d_lo];
            s += a * a;
        }
        acc += weights[g] * sqrtf(s / (28.0f * scales[g]));
    }

    red[tid] = acc;
    __syncthreads();
    for (int s = 128; s > 0; s >>= 1) {
        if (tid < s) red[tid] += red[tid + s];
        __syncthreads();
    }
    if (tid == 0) out[0] = red[0];
}

extern "C" void kernel_launch(void* const* d_in, const int* in_sizes, int n_in,
                              void* d_out, int out_size, void* d_ws, size_t ws_size,
                              hipStream_t stream) {
    const float* inp     = (const float*)d_in[0];
    const float* tgt     = (const float*)d_in[1];
    const float* scales  = (const float*)d_in[2];
    const float* weights = (const float*)d_in[3];
    // seg_ids (d_in[4]) and num_segments (d_in[5]) are recomputed analytically.

    float* ws_base = (float*)d_ws;           // 70*28 = 1960 floats
    float* ws_part = ws_base + 1960;         // nblocks floats

    const int nblocks = (I_ITEMS + IPB - 1) / IPB;   // 953

    hipMemsetAsync(ws_base, 0, 1960 * sizeof(float), stream);
    wrmsse_k1<<<nblocks, K1_BLOCK, 0, stream>>>(inp, tgt, scales, weights, ws_base, ws_part);
    wrmsse_k2<<<1, 256, 0, stream>>>(scales, weights, ws_base, ws_part, nblocks, (float*)d_out);
}

// Round 7
// 55.114 us; speedup vs baseline: 1.6750x; 1.1160x over previous
//
#include <hip/hip_runtime.h>

#define I_ITEMS 30490
#define H_HOR 28
#define ROW28 (I_ITEMS * H_HOR)      // floats per store block
#define ROWF2 (ROW28 / 2)            // float2s per store block
#define IPB 32                       // items per block
#define K1_BLOCK 448                 // 32 items * 14 float2-lanes = 7 waves
#define LSTR 11                      // LDS row stride: 10 stores + 1 pad
#define G_ITEM   154
#define G_ISTATE (154 + I_ITEMS)
#define G_ISTORE (154 + 4 * I_ITEMS)

// ws layout: [0,1960) base sums [store*7+dept][28]; [1960,...) block partials

__global__ __launch_bounds__(K1_BLOCK, 7) void wrmsse_k1(
    const float* __restrict__ inp, const float* __restrict__ tgt,
    const float* __restrict__ scales, const float* __restrict__ weights,
    float* __restrict__ ws_base, float* __restrict__ ws_part)
{
    __shared__ float lds[IPB * H_HOR * LSTR];   // [(item*28+h)*11 + st], 39.4 KB
    __shared__ float wred[7];
    const int tid = threadIdx.x;
    const int li  = tid / 14;            // local item 0..31
    const int hh2 = tid % 14;            // float2 index over h
    const int i0  = blockIdx.x * IPB;
    const int gi  = i0 + li;

    // ---- load: float2, fully coalesced (f2 index = i0*14 + tid) — round-2 form ----
    float2 d2[10];
    if (gi < I_ITEMS) {
        const float2* ip2 = (const float2*)inp;
        const float2* tp2 = (const float2*)tgt;
        const int base = i0 * 14 + tid;
        #pragma unroll
        for (int st = 0; st < 10; ++st) {
            const int idx = st * ROWF2 + base;
            float2 a = tp2[idx], b = ip2[idx];
            d2[st] = make_float2(a.x - b.x, a.y - b.y);
        }
    } else {
        #pragma unroll
        for (int st = 0; st < 10; ++st) d2[st] = make_float2(0.0f, 0.0f);
    }

    // ---- stage raw diffs: two LDS rows per thread ----
    {
        float* L0 = &lds[(li * H_HOR + 2 * hh2) * LSTR];
        float* L1 = L0 + LSTR;
        #pragma unroll
        for (int st = 0; st < 10; ++st) { L0[st] = d2[st].x; L1[st] = d2[st].y; }
    }
    __syncthreads();

    // ---- Task A: (item, v) lanes, unified store-range sum, branchless ----
    float contrib = 0.0f;
    {
        const int v = hh2;
        const int st0 = (v < 10) ? v      : (v == 10) ? 0  : (v == 11) ? 0 : (v == 12) ? 4 : 7;
        const int st1 = (v < 10) ? v + 1  : (v == 10) ? 10 : (v == 11) ? 4 : (v == 12) ? 7 : 10;
        if (gi < I_ITEMS) {
            const float* L = &lds[li * H_HOR * LSTR];
            float s = 0.0f;
            #pragma unroll
            for (int h = 0; h < H_HOR; ++h) {
                float t = 0.0f;
                for (int st = st0; st < st1; ++st) t += L[h * LSTR + st];
                s += t * t;
            }
            int g;
            if (v < 10)       g = G_ISTORE + gi * 10 + v;
            else if (v == 10) g = G_ITEM + gi;
            else              g = G_ISTATE + gi * 3 + (v - 11);
            contrib = weights[g] * sqrtf(s / (28.0f * scales[g]));
        }
    }

    // ---- Task B: (store,dept,h) base sums; dept split via boundary item ----
    {
        const int dept0 = (i0 * 7) / I_ITEMS;
        const int ib    = ((dept0 + 1) * I_ITEMS + 6) / 7;       // first item of next dept
        const int nb    = min(IPB, max(0, ib - i0));             // items in dept0
        for (int t = tid; t < 280; t += K1_BLOCK) {
            const int st = t / 28, h = t % 28;
            const float* Lc = &lds[h * LSTR + st];
            float s0 = 0.0f, s1 = 0.0f;
            #pragma unroll
            for (int l2 = 0; l2 < IPB; ++l2) {
                float x = Lc[l2 * H_HOR * LSTR];
                if (l2 < nb) s0 += x; else s1 += x;
            }
            atomicAdd(&ws_base[(st * 7 + dept0) * 28 + h], s0);
            if (nb < IPB && dept0 < 6)
                atomicAdd(&ws_base[(st * 7 + dept0 + 1) * 28 + h], s1);
        }
    }

    // ---- block contribution reduce: 7 waves ----
    float c = contrib;
    #pragma unroll
    for (int off = 32; off > 0; off >>= 1) c += __shfl_down(c, off, 64);
    if ((tid & 63) == 0) wred[tid >> 6] = c;
    __syncthreads();
    if (tid == 0) {
        float s = 0.0f;
        #pragma unroll
        for (int w = 0; w < 7; ++w) s += wred[w];
        ws_part[blockIdx.x] = s;
    }
}

__global__ __launch_bounds__(256) void wrmsse_k2(
    const float* __restrict__ scales, const float* __restrict__ weights,
    const float* __restrict__ ws_base, const float* __restrict__ ws_part,
    const int npart, float* __restrict__ out)
{
    __shared__ float P[28 * 88];   // per-h padded 2D prefix
    __shared__ float red[256];
    const int tid = threadIdx.x;

    float acc = 0.0f;
    for (int p = tid; p < npart; p += 256) acc += ws_part[p];

    if (tid < 28) {
        const int h = tid;
        float v[10][7];
        #pragma unroll
        for (int st = 0; st < 10; ++st)
            #pragma unroll
            for (int dd = 0; dd < 7; ++dd)
                v[st][dd] = ws_base[(st * 7 + dd) * 28 + h];
        #pragma unroll
        for (int st = 0; st < 10; ++st)
            #pragma unroll
            for (int dd = 1; dd < 7; ++dd) v[st][dd] += v[st][dd - 1];
        #pragma unroll
        for (int dd = 0; dd < 7; ++dd)
            #pragma unroll
            for (int st = 1; st < 10; ++st) v[st][dd] += v[st - 1][dd];
        float* Ph = &P[h * 88];
        #pragma unroll
        for (int dd = 0; dd < 8; ++dd) Ph[dd] = 0.0f;
        #pragma unroll
        for (int st = 1; st < 11; ++st) {
            Ph[st * 8] = 0.0f;
            #pragma unroll
            for (int dd = 1; dd < 8; ++dd) Ph[st * 8 + dd] = v[st - 1][dd - 1];
        }
    }
    __syncthreads();

    if (tid < 154) {
        const int g = tid;
        const int st_lo3[3] = {0, 4, 7}, st_hi3[3] = {4, 7, 10};
        const int ct_lo3[3] = {0, 3, 5}, ct_hi3[3] = {3, 5, 7};
        int s_lo, s_hi, d_lo, d_hi;
        if (g == 0)      { s_lo=0; s_hi=10; d_lo=0; d_hi=7; }
        else if (g < 4)  { int s=g-1;  s_lo=st_lo3[s]; s_hi=st_hi3[s]; d_lo=0; d_hi=7; }
        else if (g < 14) { int st=g-4; s_lo=st; s_hi=st+1; d_lo=0; d_hi=7; }
        else if (g < 17) { int c=g-14; s_lo=0; s_hi=10; d_lo=ct_lo3[c]; d_hi=ct_hi3[c]; }
        else if (g < 24) { int dd=g-17; s_lo=0; s_hi=10; d_lo=dd; d_hi=dd+1; }
        else if (g < 33) { int l=g-24, s=l/3, c=l%3;
                           s_lo=st_lo3[s]; s_hi=st_hi3[s]; d_lo=ct_lo3[c]; d_hi=ct_hi3[c]; }
        else if (g < 54) { int l=g-33, s=l/7, dd=l%7;
                           s_lo=st_lo3[s]; s_hi=st_hi3[s]; d_lo=dd; d_hi=dd+1; }
        else if (g < 84) { int l=g-54, st=l/3, c=l%3;
                           s_lo=st; s_hi=st+1; d_lo=ct_lo3[c]; d_hi=ct_hi3[c]; }
        else             { int l=g-84, st=l/7, dd=l%7;
                           s_lo=st; s_hi=st+1; d_lo=dd; d_hi=dd+1; }
        float s = 0.0f;
        #pragma unroll
        for (int h = 0; h < 28; ++h) {
            const float* Ph = &P[h * 88];
            float a = Ph[s_hi * 8 + d_hi] - Ph[s_lo * 8 + d_hi]
                    - Ph[s_hi * 8 + d_lo] + Ph[s_lo * 8 + d_lo];
            s += a * a;
        }
        acc += weights[g] * sqrtf(s / (28.0f * scales[g]));
    }

    red[tid] = acc;
    __syncthreads();
    for (int s = 128; s > 0; s >>= 1) {
        if (tid < s) red[tid] += red[tid + s];
        __syncthreads();
    }
    if (tid == 0) out[0] = red[0];
}

extern "C" void kernel_launch(void* const* d_in, const int* in_sizes, int n_in,
                              void* d_out, int out_size, void* d_ws, size_t ws_size,
                              hipStream_t stream) {
    const float* inp     = (const float*)d_in[0];
    const float* tgt     = (const float*)d_in[1];
    const float* scales  = (const float*)d_in[2];
    const float* weights = (const float*)d_in[3];
    // seg_ids (d_in[4]) and num_segments (d_in[5]) are recomputed analytically.

    float* ws_base = (float*)d_ws;           // 70*28 = 1960 floats
    float* ws_part = ws_base + 1960;         // nblocks floats

    const int nblocks = (I_ITEMS + IPB - 1) / IPB;   // 953

    hipMemsetAsync(ws_base, 0, 1960 * sizeof(float), stream);
    wrmsse_k1<<<nblocks, K1_BLOCK, 0, stream>>>(inp, tgt, scales, weights, ws_base, ws_part);
    wrmsse_k2<<<1, 256, 0, stream>>>(scales, weights, ws_base, ws_part, nblocks, (float*)d_out);
}

// Round 8
// 50.202 us; speedup vs baseline: 1.8389x; 1.0979x over previous
//
#include <hip/hip_runtime.h>

#define I_ITEMS 30490
#define H_HOR 28
#define ROW28 (I_ITEMS * H_HOR)      // floats per store block
#define ROWF2 (ROW28 / 2)            // float2s per store block
#define IPB 32                       // items per block
#define K1_BLOCK 512                 // 32 items * 16 lanes = 8 waves
#define G_ITEM   154
#define G_ISTATE (154 + I_ITEMS)
#define G_ISTORE (154 + 4 * I_ITEMS)

__device__ __forceinline__ float dot2(float2 a) { return a.x * a.x + a.y * a.y; }
__device__ __forceinline__ float2 f2add(float2 a, float2 b) {
    return make_float2(a.x + b.x, a.y + b.y);
}

// ws layout: [0,1960) base sums [store*7+dept][28]; [1960,...) block partials

__global__ __launch_bounds__(K1_BLOCK, 6) void wrmsse_k1(
    const float* __restrict__ inp, const float* __restrict__ tgt,
    const float* __restrict__ scales, const float* __restrict__ weights,
    float* __restrict__ ws_base, float* __restrict__ ws_part)
{
    __shared__ float tb[8 * 280];      // [wave][st*28+h] per-wave Task-B sums (9 KB)
    __shared__ float wred[8];
    const int tid  = threadIdx.x;
    const int lane = tid & 63;
    const int wv   = tid >> 6;
    const int li   = tid >> 4;         // local item 0..31
    const int j    = tid & 15;         // h-pair lane; active j<14 (h = 2j, 2j+1)
    const int i0   = blockIdx.x * IPB;
    const int gi   = i0 + li;
    const bool act = (gi < I_ITEMS) && (j < 14);

    const int iLast = min(i0 + IPB - 1, I_ITEMS - 1);
    const int dept0 = (i0 * 7) / I_ITEMS;
    const bool uniform = (dept0 == ((iLast * 7) / I_ITEMS));

    // ---- loads: float2, coalesced (group g covers item gi's 14 f2 contiguously) ----
    float2 d2[10];
    if (act) {
        const float2* tp2 = (const float2*)tgt;
        const float2* ip2 = (const float2*)inp;
        const int base = gi * 14 + j;
        #pragma unroll
        for (int st = 0; st < 10; ++st) {
            float2 a = tp2[st * ROWF2 + base], b = ip2[st * ROWF2 + base];
            d2[st] = make_float2(a.x - b.x, a.y - b.y);
        }
    } else {
        #pragma unroll
        for (int st = 0; st < 10; ++st) d2[st] = make_float2(0.0f, 0.0f);
    }

    // ---- per-lane partial squared sums (2 h's each): 14 values ----
    float p[14];
    #pragma unroll
    for (int st = 0; st < 10; ++st) p[st] = dot2(d2[st]);
    float2 ca = f2add(f2add(d2[0], d2[1]), f2add(d2[2], d2[3]));
    float2 tx = f2add(f2add(d2[4], d2[5]), d2[6]);
    float2 wi = f2add(f2add(d2[7], d2[8]), d2[9]);
    p[10] = dot2(ca); p[11] = dot2(tx); p[12] = dot2(wi);
    p[13] = dot2(f2add(f2add(ca, tx), wi));

    // ---- Task B: sum the wave's 4 items in-register (xor 16, 32), stage per wave ----
    if (uniform) {
        #pragma unroll
        for (int st = 0; st < 10; ++st) {
            d2[st].x += __shfl_xor(d2[st].x, 16, 64);
            d2[st].y += __shfl_xor(d2[st].y, 16, 64);
            d2[st].x += __shfl_xor(d2[st].x, 32, 64);
            d2[st].y += __shfl_xor(d2[st].y, 32, 64);
        }
        if (lane < 14) {                           // quarter-0 lanes hold wave sums
            #pragma unroll
            for (int st = 0; st < 10; ++st)
                *(float2*)&tb[wv * 280 + st * 28 + 2 * lane] = d2[st];
        }
    } else if (act) {                              // rare dept-boundary block (6/953)
        const int di = (gi * 7) / I_ITEMS;
        #pragma unroll
        for (int st = 0; st < 10; ++st) {
            atomicAdd(&ws_base[(st * 7 + di) * 28 + 2 * j],     d2[st].x);
            atomicAdd(&ws_base[(st * 7 + di) * 28 + 2 * j + 1], d2[st].y);
        }
    }

    // ---- Task A: butterfly over the 16-lane item group (masks 1,2,4,8) ----
    #pragma unroll
    for (int v = 0; v < 14; ++v) {
        p[v] += __shfl_xor(p[v], 1, 64);
        p[v] += __shfl_xor(p[v], 2, 64);
        p[v] += __shfl_xor(p[v], 4, 64);
        p[v] += __shfl_xor(p[v], 8, 64);
    }
    float contrib = 0.0f;
    if (act) {
        const int v = j;
        float s = p[0];                            // static select chain (no reg indexing)
        if (v == 1)  s = p[1];  if (v == 2)  s = p[2];  if (v == 3)  s = p[3];
        if (v == 4)  s = p[4];  if (v == 5)  s = p[5];  if (v == 6)  s = p[6];
        if (v == 7)  s = p[7];  if (v == 8)  s = p[8];  if (v == 9)  s = p[9];
        if (v == 10) s = p[10]; if (v == 11) s = p[11]; if (v == 12) s = p[12];
        if (v == 13) s = p[13];
        int g;
        if (v < 10)      g = G_ISTORE + gi * 10 + v;
        else if (v < 13) g = G_ISTATE + gi * 3 + (v - 10);
        else             g = G_ITEM + gi;
        contrib = weights[g] * sqrtf(s / (28.0f * scales[g]));
    }

    __syncthreads();

    // ---- flush per-block (store,dept0,h) sums: 280 cells, 8-wave combine ----
    if (uniform) {
        for (int t = tid; t < 280; t += K1_BLOCK) {
            float s = 0.0f;
            #pragma unroll
            for (int w = 0; w < 8; ++w) s += tb[w * 280 + t];
            atomicAdd(&ws_base[((t / 28) * 7 + dept0) * 28 + (t % 28)], s);
        }
    }

    // ---- block contribution reduce: 8 waves ----
    float c = contrib;
    #pragma unroll
    for (int off = 32; off > 0; off >>= 1) c += __shfl_down(c, off, 64);
    if (lane == 0) wred[wv] = c;
    __syncthreads();
    if (tid == 0) {
        float s = 0.0f;
        #pragma unroll
        for (int w = 0; w < 8; ++w) s += wred[w];
        ws_part[blockIdx.x] = s;
    }
}

__global__ __launch_bounds__(256) void wrmsse_k2(
    const float* __restrict__ scales, const float* __restrict__ weights,
    const float* __restrict__ ws_base, const float* __restrict__ ws_part,
    const int npart, float* __restrict__ out)
{
    __shared__ float P[28 * 88];   // per-h padded 2D prefix
    __shared__ float red[256];
    const int tid = threadIdx.x;

    float acc = 0.0f;
    for (int p = tid; p < npart; p += 256) acc += ws_part[p];

    if (tid < 28) {
        const int h = tid;
        float v[10][7];
        #pragma unroll
        for (int st = 0; st < 10; ++st)
            #pragma unroll
            for (int dd = 0; dd < 7; ++dd)
                v[st][dd] = ws_base[(st * 7 + dd) * 28 + h];
        #pragma unroll
        for (int st = 0; st < 10; ++st)
            #pragma unroll
            for (int dd = 1; dd < 7; ++dd) v[st][dd] += v[st][dd - 1];
        #pragma unroll
        for (int dd = 0; dd < 7; ++dd)
            #pragma unroll
            for (int st = 1; st < 10; ++st) v[st][dd] += v[st - 1][dd];
        float* Ph = &P[h * 88];
        #pragma unroll
        for (int dd = 0; dd < 8; ++dd) Ph[dd] = 0.0f;
        #pragma unroll
        for (int st = 1; st < 11; ++st) {
            Ph[st * 8] = 0.0f;
            #pragma unroll
            for (int dd = 1; dd < 8; ++dd) Ph[st * 8 + dd] = v[st - 1][dd - 1];
        }
    }
    __syncthreads();

    if (tid < 154) {
        const int g = tid;
        const int st_lo3[3] = {0, 4, 7}, st_hi3[3] = {4, 7, 10};
        const int ct_lo3[3] = {0, 3, 5}, ct_hi3[3] = {3, 5, 7};
        int s_lo, s_hi, d_lo, d_hi;
        if (g == 0)      { s_lo=0; s_hi=10; d_lo=0; d_hi=7; }
        else if (g < 4)  { int s=g-1;  s_lo=st_lo3[s]; s_hi=st_hi3[s]; d_lo=0; d_hi=7; }
        else if (g < 14) { int st=g-4; s_lo=st; s_hi=st+1; d_lo=0; d_hi=7; }
        else if (g < 17) { int c=g-14; s_lo=0; s_hi=10; d_lo=ct_lo3[c]; d_hi=ct_hi3[c]; }
        else if (g < 24) { int dd=g-17; s_lo=0; s_hi=10; d_lo=dd; d_hi=dd+1; }
        else if (g < 33) { int l=g-24, s=l/3, c=l%3;
                           s_lo=st_lo3[s]; s_hi=st_hi3[s]; d_lo=ct_lo3[c]; d_hi=ct_hi3[c]; }
        else if (g < 54) { int l=g-33, s=l/7, dd=l%7;
                           s_lo=st_lo3[s]; s_hi=st_hi3[s]; d_lo=dd; d_hi=dd+1; }
        else if (g < 84) { int l=g-54, st=l/3, c=l%3;
                           s_lo=st; s_hi=st+1; d_lo=ct_lo3[c]; d_hi=ct_hi3[c]; }
        else             { int l=g-84, st=l/7, dd=l%7;
                           s_lo=st; s_hi=st+1; d_lo=dd; d_hi=dd+1; }
        float s = 0.0f;
        #pragma unroll
        for (int h = 0; h < 28; ++h) {
            const float* Ph = &P[h * 88];
            float a = Ph[s_hi * 8 + d_hi] - Ph[s_lo * 8 + d_hi]
                    - Ph[s_hi * 8 + d_lo] + Ph[s_lo * 8 + d_lo];
            s += a * a;
        }
        acc += weights[g] * sqrtf(s / (28.0f * scales[g]));
    }

    red[tid] = acc;
    __syncthreads();
    for (int s = 128; s > 0; s >>= 1) {
        if (tid < s) red[tid] += red[tid + s];
        __syncthreads();
    }
    if (tid == 0) out[0] = red[0];
}

extern "C" void kernel_launch(void* const* d_in, const int* in_sizes, int n_in,
                              void* d_out, int out_size, void* d_ws, size_t ws_size,
                              hipStream_t stream) {
    const float* inp     = (const float*)d_in[0];
    const float* tgt     = (const float*)d_in[1];
    const float* scales  = (const float*)d_in[2];
    const float* weights = (const float*)d_in[3];
    // seg_ids (d_in[4]) and num_segments (d_in[5]) are recomputed analytically.

    float* ws_base = (float*)d_ws;           // 70*28 = 1960 floats
    float* ws_part = ws_base + 1960;         // nblocks floats

    const int nblocks = (I_ITEMS + IPB - 1) / IPB;   // 953

    hipMemsetAsync(ws_base, 0, 1960 * sizeof(float), stream);
    wrmsse_k1<<<nblocks, K1_BLOCK, 0, stream>>>(inp, tgt, scales, weights, ws_base, ws_part);
    wrmsse_k2<<<1, 256, 0, stream>>>(scales, weights, ws_base, ws_part, nblocks, (float*)d_out);
}